// Round 5
// baseline (144.793 us; speedup 1.0000x reference)
//
#include <hip/hip_runtime.h>

namespace {

constexpr int B_N = 8;
constexpr int A_N = 100000;
constexpr int M_N = 128;
constexpr int BLOCK = 256;
constexpr int NBLK  = (A_N + BLOCK - 1) / BLOCK;   // 391
constexpr int NWORD = NBLK * 4;                    // 1564 ballot words / image
constexpr int KB_BLOCKS = 64;                      // pos-pass blocks per image

// workspace layout (bytes)
constexpr size_t OFF_CLS = 0;                                          // B*NBLK f32
constexpr size_t OFF_CNT = OFF_CLS + (size_t)B_N * NBLK * 4;           // B*NBLK u32
constexpr size_t OFF_BAL = ((OFF_CNT + (size_t)B_N * NBLK * 4) + 7) & ~size_t(7);  // B*NWORD u64
constexpr size_t OFF_PP  = OFF_BAL + (size_t)B_N * NWORD * 8;          // B*KB_BLOCKS*3 f32

__device__ __forceinline__ float f4c(const float4& v, int j) {
    return j == 0 ? v.x : j == 1 ? v.y : j == 2 ? v.z : v.w;
}

// ---------------------------------------------------------------------------
// KA: fused box-prep + band test + cls focal-neg sum + ballots.
// Band test (no argmax):  pos ⟺ max_m(3·in − ba) ≥ aarea  (iou ≥ 0.5)
//                         neg ⟺ max_m(3.5·in − ba) < aarea (iou < 0.4)
// ~10-11 VALU/box with v_max3 pairing; boxes broadcast from LDS.
// ---------------------------------------------------------------------------
__global__ __launch_bounds__(BLOCK) void ka_main(
    const float* __restrict__ cls_,      // (B, A, 8)
    const float* __restrict__ anchors_,  // (1, A, 4)
    const float* __restrict__ ann_,      // (B, M, 18)
    float* __restrict__ clsneg,          // (B*NBLK)
    unsigned* __restrict__ counts,       // (B*NBLK)
    unsigned long long* __restrict__ ballots)  // (B*NWORD)
{
    __shared__ float4 s_bb[M_N];
    __shared__ __align__(16) float s_nb[M_N];   // -box_area; invalid -> -1e30

    const int b = blockIdx.y, blk = blockIdx.x, tid = threadIdx.x;
    const int a  = blk * BLOCK + tid;
    const int ca = min(a, A_N - 1);

    // prefetch globals (overlap with LDS prep)
    const float4 an = ((const float4*)anchors_)[ca];
    const float* cp = cls_ + ((size_t)b * A_N + ca) * 8;
    const float4 cA = ((const float4*)cp)[0];
    const float4 cB = ((const float4*)cp)[1];

    if (tid < M_N) {
        const float* t = ann_ + ((size_t)b * M_N + tid) * 18;
        float minx = t[0], maxx = t[0], miny = t[1], maxy = t[1];
#pragma unroll
        for (int j = 1; j < 8; ++j) {
            const float x = t[2 * j], y = t[2 * j + 1];
            minx = fminf(minx, x); maxx = fmaxf(maxx, x);
            miny = fminf(miny, y); maxy = fmaxf(maxy, y);
        }
        float nba = -((maxx - minx) * (maxy - miny));
        if (t[17] < 0.0f) {  // invalid: in=0 and never drives pos/neg bands up
            minx = 1e30f; miny = 1e30f; maxx = -1e30f; maxy = -1e30f; nba = -1e30f;
        }
        s_bb[tid] = make_float4(minx, miny, maxx, maxy);
        s_nb[tid] = nba;
    }
    __syncthreads();

    const float aarea = (an.z - an.x) * (an.w - an.y);
    float m1 = -3e38f, m2 = -3e38f;

#pragma unroll 2
    for (int m = 0; m < M_N; m += 4) {
        const float4 nb = ((const float4*)s_nb)[m >> 2];
        float t1[4], t2[4];
#pragma unroll
        for (int j = 0; j < 4; ++j) {
            const float4 bb = s_bb[m + j];
            const float nbj = f4c(nb, j);
            const float iw = fminf(an.z, bb.z) - fmaxf(an.x, bb.x);
            const float ih = fminf(an.w, bb.w) - fmaxf(an.y, bb.y);
            const float in_ = fmaxf(iw, 0.f) * fmaxf(ih, 0.f);
            t1[j] = __builtin_fmaf(3.0f, in_, nbj);
            t2[j] = __builtin_fmaf(3.5f, in_, nbj);
        }
        m1 = fmaxf(fmaxf(m1, fmaxf(t1[0], t1[1])), fmaxf(t1[2], t1[3]));
        m2 = fmaxf(fmaxf(m2, fmaxf(t2[0], t2[1])), fmaxf(t2[2], t2[3]));
    }

    const bool inb = (a < A_N);
    const bool pos = inb && (m1 >= aarea);
    const bool nonign = pos || (m2 < aarea);   // pos or neg

    float clsS;
    {
        const float pv[8] = {cA.x, cA.y, cA.z, cA.w, cB.x, cB.y, cB.z, cB.w};
        float s = 0.f;
#pragma unroll
        for (int c = 0; c < 8; ++c) {
            const float p = fminf(fmaxf(pv[c], 1e-4f), 1.0f - 1e-4f);
            s += 0.75f * p * p * (-__logf(1.0f - p));
        }
        clsS = (inb && nonign) ? s : 0.f;
    }

    const unsigned long long word = __ballot(pos);
    const int wv = tid >> 6, ln = tid & 63;

#pragma unroll
    for (int off = 32; off; off >>= 1) clsS += __shfl_down(clsS, off);

    __shared__ float s_c[4];
    __shared__ unsigned s_p[4];
    if (ln == 0) {
        s_c[wv] = clsS;
        s_p[wv] = (unsigned)__popcll(word);
        ballots[((size_t)b * NBLK + blk) * 4 + wv] = word;
    }
    __syncthreads();
    if (tid == 0) {
        clsneg[b * NBLK + blk] = s_c[0] + s_c[1] + s_c[2] + s_c[3];
        counts[b * NBLK + blk] = s_p[0] + s_p[1] + s_p[2] + s_p[3];
    }
}

// ---------------------------------------------------------------------------
// KB: pos-anchor pass straight from ballots (no scan/compact/list).
// Grid (KB_BLOCKS, B). Each wave walks its words; per set bit the whole wave
// cooperates: lane l covers boxes l and l+64; first-wins butterfly reduce
// (iou desc, idx asc — division-free compare); epilogue computed redundantly
// by all lanes, lane 0 accumulates. All sums unnormalized (KC normalizes).
// ---------------------------------------------------------------------------
__global__ __launch_bounds__(BLOCK) void kb_pos(
    const float* __restrict__ cls_,
    const float* __restrict__ reg_,
    const float* __restrict__ anchors_,
    const float* __restrict__ ann_,
    const unsigned long long* __restrict__ ballots,
    float* __restrict__ pospart)         // (B*KB_BLOCKS, 3)
{
    __shared__ float  s_ann[M_N * 18];
    __shared__ float4 s_bb[M_N];
    __shared__ float  s_ba[M_N];
    __shared__ float  s_red[4][3];

    const int b = blockIdx.y, tid = threadIdx.x;
    const int wv = tid >> 6, ln = tid & 63;

    const float* annb = ann_ + (size_t)b * M_N * 18;
    for (int i = tid; i < M_N * 18; i += BLOCK) s_ann[i] = annb[i];
    __syncthreads();
    if (tid < M_N) {
        const float* t = s_ann + tid * 18;
        float minx = t[0], maxx = t[0], miny = t[1], maxy = t[1];
#pragma unroll
        for (int j = 1; j < 8; ++j) {
            const float x = t[2 * j], y = t[2 * j + 1];
            minx = fminf(minx, x); maxx = fmaxf(maxx, x);
            miny = fminf(miny, y); maxy = fmaxf(maxy, y);
        }
        float area = (maxx - minx) * (maxy - miny);
        if (t[17] < 0.0f) {  // invalid: in=0, strict '>' means it never wins
            minx = 1e30f; miny = 1e30f; maxx = -1e30f; maxy = -1e30f; area = 0.f;
        }
        s_bb[tid] = make_float4(minx, miny, maxx, maxy);
        s_ba[tid] = area;
    }
    __syncthreads();

    float accC = 0.f, accR = 0.f, accV = 0.f;

    for (int wd = blockIdx.x * 4 + wv; wd < NWORD; wd += KB_BLOCKS * 4) {
        unsigned long long w = ballots[(size_t)b * NWORD + wd];  // wave-uniform
        const int abase = (wd >> 2) * BLOCK + (wd & 3) * 64;
        while (w) {
            const int bit = __builtin_ctzll(w);
            w &= w - 1;
            const int a = abase + bit;

            const float4 an = ((const float4*)anchors_)[a];  // uniform broadcast
            const float aarea = (an.z - an.x) * (an.w - an.y);

            // lane-local: boxes ln and ln+64 (first-wins: keep lower unless >)
            float bn, bu; int kb;
            {
                const float4 bb = s_bb[ln];
                const float iw = fminf(an.z, bb.z) - fmaxf(an.x, bb.x);
                const float ih = fminf(an.w, bb.w) - fmaxf(an.y, bb.y);
                bn = fmaxf(iw, 0.f) * fmaxf(ih, 0.f);
                bu = aarea + s_ba[ln] - bn;
                kb = ln;
            }
            {
                const float4 bb = s_bb[ln + 64];
                const float iw = fminf(an.z, bb.z) - fmaxf(an.x, bb.x);
                const float ih = fminf(an.w, bb.w) - fmaxf(an.y, bb.y);
                const float in1 = fmaxf(iw, 0.f) * fmaxf(ih, 0.f);
                const float ua1 = aarea + s_ba[ln + 64] - in1;
                if (in1 * bu > bn * ua1) { bn = in1; bu = ua1; kb = ln + 64; }
            }
            // butterfly reduce with (iou desc, idx asc) — order-independent
#pragma unroll
            for (int off = 32; off; off >>= 1) {
                const float oin = __shfl_down(bn, off);
                const float oua = __shfl_down(bu, off);
                const int   okb = __shfl_down(kb, off);
                const float p1 = oin * bu, p2 = bn * oua;
                const bool take = (p1 > p2) || ((p1 == p2) && (okb < kb));
                bn = take ? oin : bn;
                bu = take ? oua : bu;
                kb = take ? okb : kb;
            }
            const int kwin = __shfl(kb, 0);

            // epilogue (all lanes redundantly; lane0 accumulates)
            const float* t = s_ann + kwin * 18;
            float tt[16];
#pragma unroll
            for (int j = 0; j < 16; ++j) tt[j] = t[j];
            const int kc = (int)t[17];

            const float praw = cls_[((size_t)b * A_N + a) * 8 + kc];
            const float p = fminf(fmaxf(praw, 1e-4f), 1.0f - 1e-4f);
            const float negkc   = 0.75f * p * p * (-__logf(1.0f - p));
            const float posterm = 0.25f * (1.0f - p) * (1.0f - p) * (-__logf(p));
            const float dC = posterm - negkc;

            const float aw  = an.z - an.x;
            const float ah  = an.w - an.y;
            const float acx = an.x + 0.5f * aw;
            const float acy = an.y + 0.5f * ah;
            const float* rp = reg_ + ((size_t)b * A_N + a) * 8;
            const float4 r0 = ((const float4*)rp)[0];
            const float4 r1 = ((const float4*)rp)[1];

            auto vp = [](float rx, float ry, float tx, float ty) {
                const float denom = sqrtf(rx * rx + ry * ry) * sqrtf(tx * tx + ty * ty);
                return 1.0f - (rx * tx + ry * ty) / fmaxf(denom, 1e-8f);
            };
            const float vp1 = vp(r0.z, r0.w,
                (tt[4] + tt[6] + tt[12] + tt[14] - (tt[0] + tt[2] + tt[8] + tt[10])) * 0.25f,
                (tt[5] + tt[7] + tt[13] + tt[15] - (tt[1] + tt[3] + tt[9] + tt[11])) * 0.25f);
            const float vp2 = vp(r1.x, r1.y,
                (tt[2] + tt[6] + tt[10] + tt[14] - (tt[0] + tt[4] + tt[8] + tt[12])) * 0.25f,
                (tt[3] + tt[7] + tt[11] + tt[15] - (tt[1] + tt[5] + tt[9] + tt[13])) * 0.25f);
            const float vp3 = vp(r1.z, r1.w,
                (tt[0] + tt[2] + tt[4] + tt[6] - (tt[8] + tt[10] + tt[12] + tt[14])) * 0.25f,
                (tt[1] + tt[3] + tt[5] + tt[7] - (tt[9] + tt[11] + tt[13] + tt[15])) * 0.25f);
            const float dV = (vp1 + vp2 + vp3) * (1.0f / 3.0f);

            const float s2[8] = {-1, -1, 1, 1, -1, -1, 1, 1};
            const float s4[8] = {-1, 1, -1, 1, -1, 1, -1, 1};
            const float s6[8] = {1, 1, 1, 1, -1, -1, -1, -1};
            float ssum = 0.f;
#pragma unroll
            for (int j = 0; j < 8; ++j) {
                const float px = r0.x + r0.z * s2[j] + r1.x * s4[j] + r1.z * s6[j];
                const float py = r0.y + r0.w * s2[j] + r1.y * s4[j] + r1.w * s6[j];
                const float tx = (tt[2 * j]     - acx) / aw;
                const float ty = (tt[2 * j + 1] - acy) / ah;
                const float dx = fabsf(px - tx);
                const float dy = fabsf(py - ty);
                ssum += (dx <= (1.0f / 9.0f)) ? 4.5f * dx * dx : dx - (0.5f / 9.0f);
                ssum += (dy <= (1.0f / 9.0f)) ? 4.5f * dy * dy : dy - (0.5f / 9.0f);
            }
            const float dR = ssum * (1.0f / 16.0f);

            if (ln == 0) { accC += dC; accR += dR; accV += dV; }
        }
    }

    if (ln == 0) { s_red[wv][0] = accC; s_red[wv][1] = accR; s_red[wv][2] = accV; }
    __syncthreads();
    if (tid == 0) {
        float C = 0, R = 0, V = 0;
        for (int w2 = 0; w2 < 4; ++w2) {
            C += s_red[w2][0]; R += s_red[w2][1]; V += s_red[w2][2];
        }
        float* o = pospart + ((size_t)b * KB_BLOCKS + blockIdx.x) * 3;
        o[0] = C; o[1] = R; o[2] = V;
    }
}

// ---------------------------------------------------------------------------
// KC: finisher. Per-image num_pos + cls base sum from KA outputs; scale all
// terms by 1/num_pos; batch-average. One block, fixed reduction order.
// ---------------------------------------------------------------------------
__global__ __launch_bounds__(BLOCK) void kc_final(
    const float* __restrict__ clsneg,
    const unsigned* __restrict__ counts,
    const float* __restrict__ pospart,
    float* __restrict__ out)
{
    const int t = threadIdx.x, wv = t >> 6, ln = t & 63;
    __shared__ float s_inv[B_N], s_cb[B_N];
    __shared__ float sw[4][2];
    __shared__ float sr[4][3];

    for (int b = 0; b < B_N; ++b) {
        float np = 0.f, cs = 0.f;
        for (int i = t; i < NBLK; i += BLOCK) {
            np += (float)counts[b * NBLK + i];
            cs += clsneg[b * NBLK + i];
        }
#pragma unroll
        for (int off = 32; off; off >>= 1) {
            np += __shfl_down(np, off);
            cs += __shfl_down(cs, off);
        }
        if (ln == 0) { sw[wv][0] = np; sw[wv][1] = cs; }
        __syncthreads();
        if (t == 0) {
            const float NP = sw[0][0] + sw[1][0] + sw[2][0] + sw[3][0];
            const float CS = sw[0][1] + sw[1][1] + sw[2][1] + sw[3][1];
            s_inv[b] = 1.0f / fmaxf(NP, 1.0f);
            s_cb[b]  = CS;
        }
        __syncthreads();
    }

    float oc = 0.f, orr = 0.f, ov = 0.f;
    for (int i = t; i < B_N * KB_BLOCKS; i += BLOCK) {
        const float inv = s_inv[i >> 6];   // KB_BLOCKS == 64
        oc  += pospart[i * 3 + 0] * inv;
        orr += pospart[i * 3 + 1] * inv;
        ov  += pospart[i * 3 + 2] * inv;
    }
#pragma unroll
    for (int off = 32; off; off >>= 1) {
        oc += __shfl_down(oc, off);
        orr += __shfl_down(orr, off);
        ov += __shfl_down(ov, off);
    }
    if (ln == 0) { sr[wv][0] = oc; sr[wv][1] = orr; sr[wv][2] = ov; }
    __syncthreads();
    if (t == 0) {
        float C = sr[0][0] + sr[1][0] + sr[2][0] + sr[3][0];
        float R = sr[0][1] + sr[1][1] + sr[2][1] + sr[3][1];
        float V = sr[0][2] + sr[1][2] + sr[2][2] + sr[3][2];
        for (int b = 0; b < B_N; ++b) C += s_cb[b] * s_inv[b];
        out[0] = C * 0.125f;
        out[1] = R * 0.125f;
        out[2] = V * 0.125f;
    }
}

}  // namespace

extern "C" void kernel_launch(void* const* d_in, const int* in_sizes, int n_in,
                              void* d_out, int out_size, void* d_ws, size_t ws_size,
                              hipStream_t stream)
{
    const float* cls_    = (const float*)d_in[0];
    const float* reg_    = (const float*)d_in[1];
    const float* anchors = (const float*)d_in[2];
    const float* ann     = (const float*)d_in[3];
    // d_in[4] embeddings: unused by the reference.

    char* ws = (char*)d_ws;
    float*              clsneg  = (float*)(ws + OFF_CLS);
    unsigned*           counts  = (unsigned*)(ws + OFF_CNT);
    unsigned long long* ballots = (unsigned long long*)(ws + OFF_BAL);
    float*              pospart = (float*)(ws + OFF_PP);

    ka_main<<<dim3(NBLK, B_N), dim3(BLOCK), 0, stream>>>(cls_, anchors, ann,
                                                         clsneg, counts, ballots);
    kb_pos<<<dim3(KB_BLOCKS, B_N), dim3(BLOCK), 0, stream>>>(cls_, reg_, anchors, ann,
                                                             ballots, pospart);
    kc_final<<<dim3(1), dim3(BLOCK), 0, stream>>>(clsneg, counts, pospart, (float*)d_out);
}

// Round 6
// 65.114 us; speedup vs baseline: 2.2237x; 2.2237x over previous
//
#include <hip/hip_runtime.h>

namespace {

constexpr int B_N = 8;
constexpr int A_N = 100000;
constexpr int M_N = 128;
constexpr int BLOCK = 256;
constexpr int NBLK = (A_N + BLOCK - 1) / BLOCK;  // 391
constexpr int GX = 16, GY = 9, NC = GX * GY;     // 144 cells of 120x120
constexpr float CELL = 120.0f;
constexpr float MARGIN = 128.0f;                 // max anchor half-extent

// workspace layout (bytes)
constexpr size_t OFF_BOX  = 0;                                 // B*M*8 f32 (32 KB)
constexpr size_t OFF_MASK = OFF_BOX + (size_t)B_N * M_N * 8 * 4;   // B*NC*2 u64 (18 KB)
constexpr size_t OFF_PART = OFF_MASK + (size_t)B_N * NC * 2 * 8;   // B*NBLK*4 f32

// ---------------------------------------------------------------------------
// K0 (validated R4): box2d records {x1,y1,x2,y2,area,0,0,0}; invalid ->
// coords (+1e30,+1e30,-1e30,-1e30), area 0.
// ---------------------------------------------------------------------------
__global__ void k0_prep(const float* __restrict__ ann_, float* __restrict__ boxbuf)
{
    const int i = blockIdx.x * blockDim.x + threadIdx.x;
    if (i >= B_N * M_N) return;
    const float* t = ann_ + (size_t)i * 18;
    float minx = t[0], maxx = t[0], miny = t[1], maxy = t[1];
#pragma unroll
    for (int j = 1; j < 8; ++j) {
        const float xj = t[2 * j], yj = t[2 * j + 1];
        minx = fminf(minx, xj); maxx = fmaxf(maxx, xj);
        miny = fminf(miny, yj); maxy = fmaxf(maxy, yj);
    }
    float area = (maxx - minx) * (maxy - miny);
    if (t[17] < 0.0f) {
        minx = 1e30f; miny = 1e30f; maxx = -1e30f; maxy = -1e30f; area = 0.0f;
    }
    float* o = boxbuf + (size_t)i * 8;
    o[0] = minx; o[1] = miny; o[2] = maxx; o[3] = maxy;
    o[4] = area; o[5] = 0.f;  o[6] = 0.f;  o[7] = 0.f;
}

// ---------------------------------------------------------------------------
// KM: per-(image,cell) 128-bit mask of boxes intersecting cell rect +- MARGIN.
// Exact filter: excluded boxes have in==0 for every anchor centered in cell.
// Invalid boxes auto-excluded (coords +-1e30 fail the intersect test).
// ---------------------------------------------------------------------------
__global__ void kmask(const float* __restrict__ boxbuf,
                      unsigned long long* __restrict__ maskbuf)  // (B*NC*2)
{
    const int cell = blockIdx.x, b = blockIdx.y, m = threadIdx.x;  // 128 thr
    const int cx = cell % GX, cy = cell / GX;
    const float lox = cx * CELL - MARGIN, hix = cx * CELL + CELL + MARGIN;
    const float loy = cy * CELL - MARGIN, hiy = cy * CELL + CELL + MARGIN;
    const float* r = boxbuf + ((size_t)b * M_N + m) * 8;
    const bool ok = (r[0] <= hix) && (r[2] >= lox) && (r[1] <= hiy) && (r[3] >= loy);
    const unsigned long long bal = __ballot(ok);
    if ((m & 63) == 0)
        maskbuf[((size_t)b * NC + cell) * 2 + (m >> 6)] = bal;
}

// ---------------------------------------------------------------------------
// KA: fused hot kernel. Per anchor: walk only masked boxes (mean ~19 of 128)
// computing in one pass (a) band maxes  m1=max(3*in-ba) [pos iff >= aarea],
// m2=max(3.5*in-ba) [neg iff < aarea], and (b) division-free first-wins
// argmax (bn, bs) for the pos epilogue (cls correction + reg + vp, inline,
// predicated). SoA LDS box arrays -> divergent reads land ~2-way (free).
// ---------------------------------------------------------------------------
__global__ __launch_bounds__(BLOCK) void ka_fused(
    const float* __restrict__ cls_,      // (B, A, 8)
    const float* __restrict__ reg_,      // (B, A, 8)
    const float* __restrict__ anchors_,  // (1, A, 4)
    const float* __restrict__ ann_,      // (B, M, 18)
    const float* __restrict__ boxbuf,
    const unsigned* __restrict__ maskbuf,  // u32 view: (B, NC, 4)
    float* __restrict__ partials)          // (B, NBLK, 4)
{
    __shared__ float s_x1[M_N], s_y1[M_N], s_x2[M_N], s_y2[M_N], s_nb[M_N];
    __shared__ unsigned s_mask[NC * 4];

    const int b = blockIdx.y, blk = blockIdx.x, tid = threadIdx.x;

    if (tid < M_N) {
        const float* r = boxbuf + ((size_t)b * M_N + tid) * 8;
        s_x1[tid] = r[0]; s_y1[tid] = r[1];
        s_x2[tid] = r[2]; s_y2[tid] = r[3];
        s_nb[tid] = -r[4];                  // negated box area
    }
    for (int i = tid; i < NC * 4; i += BLOCK)
        s_mask[i] = maskbuf[(size_t)b * NC * 4 + i];
    __syncthreads();

    const int a  = blk * BLOCK + tid;
    const int ca = min(a, A_N - 1);
    const float4 an = ((const float4*)anchors_)[ca];
    const float* cp = cls_ + ((size_t)b * A_N + ca) * 8;
    const float4 cA = ((const float4*)cp)[0];
    const float4 cB = ((const float4*)cp)[1];

    const float aarea = (an.z - an.x) * (an.w - an.y);
    const float acx = 0.5f * (an.x + an.z);
    const float acy = 0.5f * (an.y + an.w);
    const int cellx = min(GX - 1, max(0, (int)(acx * (1.0f / CELL))));
    const int celly = min(GY - 1, max(0, (int)(acy * (1.0f / CELL))));
    const int cell  = celly * GX + cellx;

    float m1 = -3e38f, m2 = -3e38f;
    float bn = 0.f, bs = 1.f;
    int   kb = 0;

#pragma unroll
    for (int q = 0; q < 4; ++q) {
        unsigned w = s_mask[cell * 4 + q];
        while (__any(w != 0u)) {
            const bool have = (w != 0u);
            const int  bit  = __ffs(w) - 1;       // -1 when w==0 (gated below)
            const int  m    = q * 32 + (have ? bit : 0);
            w &= w - 1;                           // 0 stays 0
            const float x1 = s_x1[m], y1 = s_y1[m];
            const float x2 = s_x2[m], y2 = s_y2[m];
            const float nbر = s_nb[m];
            const float nb = have ? nbر : -3e37f;
            const float iw = fminf(an.z, x2) - fmaxf(an.x, x1);
            const float ih = fminf(an.w, y2) - fmaxf(an.y, y1);
            const float in_raw = fmaxf(iw, 0.f) * fmaxf(ih, 0.f);
            const float in_ = have ? in_raw : 0.f;
            const float t1 = __builtin_fmaf(3.0f, in_, nb);
            const float t2 = __builtin_fmaf(3.5f, in_, nb);
            m1 = fmaxf(m1, t1);
            m2 = fmaxf(m2, t2);
            // first-wins argmax (validated transform): s = aarea + ba
            const float s = aarea - nb;
            const bool  u = (in_ * bs > bn * s);  // in_=0 can never fire
            bn = u ? in_ : bn;
            bs = u ? s   : bs;
            kb = u ? m   : kb;
        }
    }

    const bool inb = (a < A_N);
    const bool pos = inb && (m1 >= aarea);
    const bool nonign = pos || (m2 < aarea);

    float clsS = 0.f, regS = 0.f, vpS = 0.f, posC = 0.f;

    // focal all-negative-targets term
    const float pv[8] = {cA.x, cA.y, cA.z, cA.w, cB.x, cB.y, cB.z, cB.w};
    {
        float s = 0.f;
#pragma unroll
        for (int c = 0; c < 8; ++c) {
            const float p = fminf(fmaxf(pv[c], 1e-4f), 1.0f - 1e-4f);
            s += 0.75f * p * p * (-__logf(1.0f - p));
        }
        clsS = (inb && nonign) ? s : 0.f;
    }

    if (pos) {  // epilogue: cls correction + reg + vp (validated R3/R5 math)
        posC = 1.0f;
        const float* t = ann_ + ((size_t)b * M_N + kb) * 18;
        float tt[16];
#pragma unroll
        for (int j = 0; j < 16; ++j) tt[j] = t[j];
        const int kc = (int)t[17];

        float pkc = 0.5f;
#pragma unroll
        for (int c = 0; c < 8; ++c)
            if (c == kc) pkc = fminf(fmaxf(pv[c], 1e-4f), 1.0f - 1e-4f);
        const float negkc   = 0.75f * pkc * pkc * (-__logf(1.0f - pkc));
        const float posterm = 0.25f * (1.0f - pkc) * (1.0f - pkc) * (-__logf(pkc));
        clsS += posterm - negkc;

        const float aw = an.z - an.x;
        const float ah = an.w - an.y;
        const float* rp = reg_ + ((size_t)b * A_N + a) * 8;
        const float4 r0 = ((const float4*)rp)[0];
        const float4 r1 = ((const float4*)rp)[1];

        auto vp = [](float rx, float ry, float tx, float ty) {
            const float denom = sqrtf(rx * rx + ry * ry) * sqrtf(tx * tx + ty * ty);
            return 1.0f - (rx * tx + ry * ty) / fmaxf(denom, 1e-8f);
        };
        const float vp1 = vp(r0.z, r0.w,
            (tt[4] + tt[6] + tt[12] + tt[14] - (tt[0] + tt[2] + tt[8] + tt[10])) * 0.25f,
            (tt[5] + tt[7] + tt[13] + tt[15] - (tt[1] + tt[3] + tt[9] + tt[11])) * 0.25f);
        const float vp2 = vp(r1.x, r1.y,
            (tt[2] + tt[6] + tt[10] + tt[14] - (tt[0] + tt[4] + tt[8] + tt[12])) * 0.25f,
            (tt[3] + tt[7] + tt[11] + tt[15] - (tt[1] + tt[5] + tt[9] + tt[13])) * 0.25f);
        const float vp3 = vp(r1.z, r1.w,
            (tt[0] + tt[2] + tt[4] + tt[6] - (tt[8] + tt[10] + tt[12] + tt[14])) * 0.25f,
            (tt[1] + tt[3] + tt[5] + tt[7] - (tt[9] + tt[11] + tt[13] + tt[15])) * 0.25f);
        vpS = (vp1 + vp2 + vp3) * (1.0f / 3.0f);

        const float s2[8] = {-1, -1, 1, 1, -1, -1, 1, 1};
        const float s4[8] = {-1, 1, -1, 1, -1, 1, -1, 1};
        const float s6[8] = {1, 1, 1, 1, -1, -1, -1, -1};
        const float acx2 = an.x + 0.5f * aw;
        const float acy2 = an.y + 0.5f * ah;
        float ssum = 0.f;
#pragma unroll
        for (int j = 0; j < 8; ++j) {
            const float px = r0.x + r0.z * s2[j] + r1.x * s4[j] + r1.z * s6[j];
            const float py = r0.y + r0.w * s2[j] + r1.y * s4[j] + r1.w * s6[j];
            const float tx = (tt[2 * j]     - acx2) / aw;
            const float ty = (tt[2 * j + 1] - acy2) / ah;
            const float dx = fabsf(px - tx);
            const float dy = fabsf(py - ty);
            ssum += (dx <= (1.0f / 9.0f)) ? 4.5f * dx * dx : dx - (0.5f / 9.0f);
            ssum += (dy <= (1.0f / 9.0f)) ? 4.5f * dy * dy : dy - (0.5f / 9.0f);
        }
        regS = ssum * (1.0f / 16.0f);
    }

    // ---- block reduction (deterministic, validated tail) --------------
#pragma unroll
    for (int off = 32; off; off >>= 1) {
        clsS += __shfl_down(clsS, off);
        regS += __shfl_down(regS, off);
        vpS  += __shfl_down(vpS, off);
        posC += __shfl_down(posC, off);
    }
    __shared__ float s_red[4][4];
    const int wv = tid >> 6, ln = tid & 63;
    if (ln == 0) {
        s_red[wv][0] = clsS; s_red[wv][1] = regS;
        s_red[wv][2] = vpS;  s_red[wv][3] = posC;
    }
    __syncthreads();
    if (tid == 0) {
        float C = 0, R = 0, V = 0, P = 0;
        for (int w2 = 0; w2 < 4; ++w2) {
            C += s_red[w2][0]; R += s_red[w2][1];
            V += s_red[w2][2]; P += s_red[w2][3];
        }
        float* out = partials + ((size_t)b * NBLK + blk) * 4;
        out[0] = C; out[1] = R; out[2] = V; out[3] = P;
    }
}

// ---------------------------------------------------------------------------
// KC (validated R3): per-image sum + num_pos normalize + batch average.
// ---------------------------------------------------------------------------
__global__ __launch_bounds__(BLOCK) void kc_final(
    const float* __restrict__ partials,
    float* __restrict__ out)
{
    const int tid = threadIdx.x;
    __shared__ float s[4][4];
    __shared__ float accum[3];
    if (tid == 0) { accum[0] = 0.f; accum[1] = 0.f; accum[2] = 0.f; }

    for (int b = 0; b < B_N; ++b) {
        float c = 0.f, r = 0.f, v = 0.f, p = 0.f;
        for (int i = tid; i < NBLK; i += BLOCK) {
            const float* q = partials + ((size_t)b * NBLK + i) * 4;
            c += q[0]; r += q[1]; v += q[2]; p += q[3];
        }
#pragma unroll
        for (int off = 32; off; off >>= 1) {
            c += __shfl_down(c, off); r += __shfl_down(r, off);
            v += __shfl_down(v, off); p += __shfl_down(p, off);
        }
        const int wv = tid >> 6, ln = tid & 63;
        if (ln == 0) { s[wv][0] = c; s[wv][1] = r; s[wv][2] = v; s[wv][3] = p; }
        __syncthreads();
        if (tid == 0) {
            float C = 0, R = 0, V = 0, P = 0;
            for (int w = 0; w < 4; ++w) {
                C += s[w][0]; R += s[w][1]; V += s[w][2]; P += s[w][3];
            }
            const float np_ = fmaxf(P, 1.0f);
            accum[0] += C / np_; accum[1] += R / np_; accum[2] += V / np_;
        }
        __syncthreads();
    }
    if (tid == 0) {
        out[0] = accum[0] * 0.125f;
        out[1] = accum[1] * 0.125f;
        out[2] = accum[2] * 0.125f;
    }
}

}  // namespace

extern "C" void kernel_launch(void* const* d_in, const int* in_sizes, int n_in,
                              void* d_out, int out_size, void* d_ws, size_t ws_size,
                              hipStream_t stream)
{
    const float* cls_    = (const float*)d_in[0];
    const float* reg_    = (const float*)d_in[1];
    const float* anchors = (const float*)d_in[2];
    const float* ann     = (const float*)d_in[3];
    // d_in[4] embeddings: unused by the reference.

    char* ws = (char*)d_ws;
    float*              boxbuf  = (float*)(ws + OFF_BOX);
    unsigned long long* maskbuf = (unsigned long long*)(ws + OFF_MASK);
    float*              partials = (float*)(ws + OFF_PART);

    k0_prep<<<dim3((B_N * M_N + BLOCK - 1) / BLOCK), dim3(BLOCK), 0, stream>>>(ann, boxbuf);
    kmask<<<dim3(NC, B_N), dim3(M_N), 0, stream>>>(boxbuf, maskbuf);
    ka_fused<<<dim3(NBLK, B_N), dim3(BLOCK), 0, stream>>>(
        cls_, reg_, anchors, ann, boxbuf, (const unsigned*)maskbuf, partials);
    kc_final<<<dim3(1), dim3(BLOCK), 0, stream>>>(partials, (float*)d_out);
}